// Round 1
// baseline (412.234 us; speedup 1.0000x reference)
//
#include <hip/hip_runtime.h>
#include <math.h>

#define KDIM   512
#define NCLS   1000
#define CUTOFF 3.0f
#define MAXCAP 4096
#define BN     64
#define BK     64
#define NSTAGE (KDIM / BK)   // 8
#define FCAP   512

typedef __attribute__((ext_vector_type(8))) short  short8;
typedef __attribute__((ext_vector_type(4))) float  floatx4;

// ---- ordered-float <-> uint encoding for atomicMax on floats ----
__device__ __forceinline__ unsigned enc_f(float f) {
    unsigned u = __float_as_uint(f);
    return (u & 0x80000000u) ? ~u : (u | 0x80000000u);
}
__device__ __forceinline__ float dec_f(unsigned k) {
    unsigned u = (k & 0x80000000u) ? (k & 0x7FFFFFFFu) : ~k;
    return __uint_as_float(u);
}
// fp32 -> bf16 round-to-nearest-even
__device__ __forceinline__ unsigned short f2bf(float f) {
    unsigned u = __float_as_uint(f);
    u += 0x7FFFu + ((u >> 16) & 1u);
    return (unsigned short)(u >> 16);
}
__device__ __forceinline__ float bf2f(unsigned short h) {
    return __uint_as_float(((unsigned)h) << 16);
}

// Prep: init cnt/gmax; convert A (Brows x 512 fp32) into fragment-major bf16
// hi/lo: af slot (16B units) = ((s16*16 + c)*2 + h)*64 + lane,
// lane = kq*16 + (r&15), s16 = r>>4, c = k32-chunk, kq = k-octet within chunk.
__global__ void k_prep(const float* __restrict__ A, unsigned short* __restrict__ af,
                       unsigned* __restrict__ cnt, unsigned* __restrict__ gmax, int Brows) {
    int t = blockIdx.x * blockDim.x + threadIdx.x;
    if (t < Brows) { cnt[t] = 0u; gmax[t] = enc_f(-3.0e38f); }
    if (t >= Brows * (KDIM / 8)) return;
    int r = t >> 6;                 // row (64 k-octets per row)
    int o = t & 63;                 // k-octet index
    int s16 = r >> 4, c = o >> 2, kq = o & 3;
    int lane = kq * 16 + (r & 15);
    const float* src = A + (size_t)r * KDIM + o * 8;
    size_t bhi = ((size_t)((s16 * 16 + c) * 2 + 0) * 64 + lane) * 8;
    size_t blo = ((size_t)((s16 * 16 + c) * 2 + 1) * 64 + lane) * 8;
#pragma unroll
    for (int j = 0; j < 8; ++j) {
        float f = src[j];
        unsigned short h = f2bf(f);
        af[bhi + j] = h;
        af[blo + j] = f2bf(f - bf2f(h));
    }
}

// GEMM: block = 256 thr = 4 waves. Wave w owns rows w*64..w*64+63 (rt=4 row
// fragments) -> each B LDS read feeds 2x the MFMAs vs the 8-wave/32-row
// version (LDS-read-BW was the bottleneck: 128 ds_read_b128/stage -> 64).
// BN=64 cols, full K=512, split-bf16 3-pass MFMA, double-buffered LDS (one
// barrier/stage), B-prefetch distance 2, A-frag loads hoisted per chunk.
__global__ __launch_bounds__(256, 3) void k_gemm(
    const float* __restrict__ Bt,            // [N][512] fp32
    const unsigned short* __restrict__ af,   // A frags bf16 hi/lo
    float* __restrict__ cand_val, int* __restrict__ cand_idx,
    unsigned* __restrict__ cnt, unsigned* __restrict__ gmax,
    int N, int cap)
{
    __shared__ short8 BsH[2][512];   // 2 x 8 KB
    __shared__ short8 BsL[2][512];

    const int tid  = threadIdx.x;
    const int lane = tid & 63;
    const int wid  = tid >> 6;                 // 0..3
    const int colBase = blockIdx.x * BN;

    // ---- B staging mapping: thread loads 16 consecutive k of one col ----
    const int nl   = tid >> 2;                 // 0..63 local col
    const int kseg = (tid & 3) * 16;           // k offset within stage (0/16/32/48)
    const int gcol = colBase + nl;
    const bool colok = (gcol < N);
    const float* bsrc = Bt + (size_t)gcol * KDIM + kseg;

    int slotw[2];
#pragma unroll
    for (int oo = 0; oo < 2; ++oo) {           // two k-octets per thread
        const int k8  = kseg + oo * 8;
        const int chw = k8 >> 5;
        const int kqw = (k8 >> 3) & 3;
        const int ctw = (nl >> 4) & 3;
        const int fidw = chw * 4 + ctw;
        const int lfw  = kqw * 16 + (nl & 15);
        slotw[oo] = fidw * 64 + (lfw ^ (kqw * 2 + chw));
    }

    floatx4 acc[4][4];
#pragma unroll
    for (int rt = 0; rt < 4; ++rt)
#pragma unroll
        for (int ct = 0; ct < 4; ++ct)
            acc[rt][ct] = (floatx4){0.f, 0.f, 0.f, 0.f};

    const float4 z4 = make_float4(0.f, 0.f, 0.f, 0.f);
    // c* = stage-s data (to convert now); n* = stage-(s+1) data (in flight)
    float4 c0 = colok ? *(const float4*)(bsrc)           : z4;
    float4 c1 = colok ? *(const float4*)(bsrc + 4)       : z4;
    float4 c2 = colok ? *(const float4*)(bsrc + 8)       : z4;
    float4 c3 = colok ? *(const float4*)(bsrc + 12)      : z4;
    float4 n0 = colok ? *(const float4*)(bsrc + BK)      : z4;
    float4 n1 = colok ? *(const float4*)(bsrc + BK + 4)  : z4;
    float4 n2 = colok ? *(const float4*)(bsrc + BK + 8)  : z4;
    float4 n3 = colok ? *(const float4*)(bsrc + BK + 12) : z4;

    auto cvw = [&](int buf, float4 a0, float4 a1, float4 a2, float4 a3) {
        union { float4 v[4]; float f[16]; } P;
        P.v[0] = a0; P.v[1] = a1; P.v[2] = a2; P.v[3] = a3;
#pragma unroll
        for (int oo = 0; oo < 2; ++oo) {
            union { short8 v; unsigned short u[8]; } H, L;
#pragma unroll
            for (int j = 0; j < 8; ++j) {
                float f = P.f[oo * 8 + j];
                unsigned short h = f2bf(f);
                H.u[j] = h; L.u[j] = f2bf(f - bf2f(h));
            }
            BsH[buf][slotw[oo]] = H.v;
            BsL[buf][slotw[oo]] = L.v;
        }
    };

    // convert + write stage 0 into buf 0
    cvw(0, c0, c1, c2, c3);
    __syncthreads();

    for (int s = 0; s < NSTAGE; ++s) {
        // ---- stage s+1: move regs, issue prefetch of s+2, convert, LDS write ----
        if (s + 1 < NSTAGE) {
            c0 = n0; c1 = n1; c2 = n2; c3 = n3;
            if (s + 2 < NSTAGE) {
                const float* p = bsrc + (s + 2) * BK;
                n0 = colok ? *(const float4*)(p)      : z4;
                n1 = colok ? *(const float4*)(p + 4)  : z4;
                n2 = colok ? *(const float4*)(p + 8)  : z4;
                n3 = colok ? *(const float4*)(p + 12) : z4;
            }
            cvw((s + 1) & 1, c0, c1, c2, c3);
        }

        // ---- compute stage s from buf[s&1] ----
#pragma unroll
        for (int chunk = 0; chunk < 2; ++chunk) {
            const int cg = s * 2 + chunk;          // global k32 chunk
            short8 aH[4], aL[4];
#pragma unroll
            for (int rt = 0; rt < 4; ++rt) {       // hoisted ahead of MFMAs
                const int s16 = wid * 4 + rt;
                size_t sl = (size_t)((s16 * 16 + cg) * 2) * 64 + lane;
                aH[rt] = *(const short8*)(af + sl * 8);
                aL[rt] = *(const short8*)(af + (sl + 64) * 8);
            }
            const int g = (lane >> 4) * 2 + chunk; // reader XOR swizzle
#pragma unroll
            for (int ct = 0; ct < 4; ++ct) {
                const int idx = (chunk * 4 + ct) * 64 + (lane ^ g);
                short8 bh = BsH[s & 1][idx];
                short8 bl = BsL[s & 1][idx];
#pragma unroll
                for (int rt = 0; rt < 4; ++rt) {
                    acc[rt][ct] = __builtin_amdgcn_mfma_f32_16x16x32_bf16(aH[rt], bh, acc[rt][ct], 0, 0, 0);
                    acc[rt][ct] = __builtin_amdgcn_mfma_f32_16x16x32_bf16(aH[rt], bl, acc[rt][ct], 0, 0, 0);
                    acc[rt][ct] = __builtin_amdgcn_mfma_f32_16x16x32_bf16(aL[rt], bh, acc[rt][ct], 0, 0, 0);
                }
            }
        }
        __syncthreads();
    }

    // ---- epilogue: chunk max, running global max, candidate append ----
    // C/D layout (verified): col = lane&15, row = (lane>>4)*4 + reg
    const int q   = lane >> 4;
    const int n15 = lane & 15;
#pragma unroll
    for (int rt = 0; rt < 4; ++rt) {
#pragma unroll
        for (int reg = 0; reg < 4; ++reg) {
            const int row = wid * 64 + rt * 16 + q * 4 + reg;
            float m = fmaxf(fmaxf(acc[rt][0][reg], acc[rt][1][reg]),
                            fmaxf(acc[rt][2][reg], acc[rt][3][reg]));
#pragma unroll
            for (int off = 1; off < 16; off <<= 1) m = fmaxf(m, __shfl_xor(m, off));
            unsigned oldk = 0u;
            if (n15 == 0) oldk = atomicMax(&gmax[row], enc_f(m));
            oldk = (unsigned)__shfl((int)oldk, lane & 48);   // quad leader
            const float thr = fmaxf(dec_f(oldk), m) - CUTOFF;
#pragma unroll
            for (int ct = 0; ct < 4; ++ct) {
                const float v = acc[rt][ct][reg];
                const int col = colBase + ct * 16 + n15;
                if (v >= thr && col < N) {
                    unsigned p = atomicAdd(&cnt[row], 1u);
                    if (p < (unsigned)cap) {
                        cand_val[(size_t)row * cap + p] = v;
                        cand_idx[(size_t)row * cap + p] = col;
                    }
                }
            }
        }
    }
}

// One block per row. Parallel: compact survivors (thr = gmax-CUTOFF) into LDS,
// rank each candidate by counting (O(ns^2) over 256 threads, ns is tiny),
// deterministic Z reduction, scatter weights into a 16 KB per-row LDS image
// of all 4 k-slices, write back coalesced (covers the full output row, so no
// separate zeroing pass).
__global__ __launch_bounds__(256) void k_finalize(
    const float* __restrict__ cand_val,
    const int* __restrict__ cand_idx,
    const unsigned* __restrict__ cnt,
    const unsigned* __restrict__ gmax,
    const int* __restrict__ labels,
    float* __restrict__ out,
    int Brows, int cap)
{
    __shared__ float s_val[FCAP];
    __shared__ int   s_idx[FCAP];
    __shared__ float s_out[4 * NCLS];   // 16 KB
    __shared__ int   s_n;
    __shared__ float s_part[4];
    __shared__ float s_Z;

    const int row = blockIdx.x;
    const int tid = threadIdx.x;
    if (tid == 0) s_n = 0;
    __syncthreads();

    const float m   = dec_f(gmax[row]);
    const float thr = m - CUTOFF;
    const int n = min((int)cnt[row], cap);
    for (int i = tid; i < n; i += 256) {
        float v = cand_val[(size_t)row * cap + i];
        if (v >= thr) {
            int p = atomicAdd(&s_n, 1);
            if (p < FCAP) { s_val[p] = v; s_idx[p] = cand_idx[(size_t)row * cap + i]; }
        }
    }
    for (int c = tid; c < 4 * NCLS; c += 256) s_out[c] = 0.f;
    __syncthreads();
    const int ns = min(s_n, FCAP);

    // rank-by-counting; each thread owns candidates tid and tid+256
    float e0 = 0.f, e1 = 0.f;
    int   r0 = 0x7fffffff, r1 = 0x7fffffff;
    int   lab0 = 0, lab1 = 0;
    if (tid < ns) {
        const float v = s_val[tid]; const int ix = s_idx[tid];
        int rk = 0;
        for (int j = 0; j < ns; ++j) {
            const float vj = s_val[j];
            rk += (vj > v || (vj == v && s_idx[j] < ix)) ? 1 : 0;
        }
        r0 = rk;
        if (rk < 200) { e0 = expf((v - m) * (1.0f / 0.07f)); lab0 = labels[ix]; }
    }
    if (tid + 256 < ns) {
        const int i2 = tid + 256;
        const float v = s_val[i2]; const int ix = s_idx[i2];
        int rk = 0;
        for (int j = 0; j < ns; ++j) {
            const float vj = s_val[j];
            rk += (vj > v || (vj == v && s_idx[j] < ix)) ? 1 : 0;
        }
        r1 = rk;
        if (rk < 200) { e1 = expf((v - m) * (1.0f / 0.07f)); lab1 = labels[ix]; }
    }

    // deterministic Z: wave shfl reduce + fixed-order cross-wave sum
    float part = e0 + e1;
#pragma unroll
    for (int off = 32; off >= 1; off >>= 1) part += __shfl_down(part, off);
    if ((tid & 63) == 0) s_part[tid >> 6] = part;
    __syncthreads();
    if (tid == 0) s_Z = (s_part[0] + s_part[1]) + (s_part[2] + s_part[3]);
    __syncthreads();
    const float invZ = 1.0f / s_Z;

    if (r0 < 200) {
        const float w = e0 * invZ;
        if (r0 < 10)  atomicAdd(&s_out[0 * NCLS + lab0], w);
        if (r0 < 20)  atomicAdd(&s_out[1 * NCLS + lab0], w);
        if (r0 < 100) atomicAdd(&s_out[2 * NCLS + lab0], w);
        atomicAdd(&s_out[3 * NCLS + lab0], w);
    }
    if (r1 < 200) {
        const float w = e1 * invZ;
        if (r1 < 10)  atomicAdd(&s_out[0 * NCLS + lab1], w);
        if (r1 < 20)  atomicAdd(&s_out[1 * NCLS + lab1], w);
        if (r1 < 100) atomicAdd(&s_out[2 * NCLS + lab1], w);
        atomicAdd(&s_out[3 * NCLS + lab1], w);
    }
    __syncthreads();

    for (int c = tid; c < 4 * NCLS; c += 256) {
        const int sl = c / NCLS, cc = c - sl * NCLS;
        out[(size_t)sl * ((size_t)Brows * NCLS) + (size_t)row * NCLS + cc] = s_out[c];
    }
}

extern "C" void kernel_launch(void* const* d_in, const int* in_sizes, int n_in,
                              void* d_out, int out_size, void* d_ws, size_t ws_size,
                              hipStream_t stream) {
    const float* A      = (const float*)d_in[0];   // (256, 512)
    const float* Bt     = (const float*)d_in[1];   // (100000, 512)
    const int*   labels = (const int*)d_in[2];     // (100000,)
    float* out = (float*)d_out;                    // (4, 256, 1000)

    const int Brows = in_sizes[0] / KDIM;          // 256
    const int N     = in_sizes[2];                 // 100000

    // ws layout: af (Brows*512*2 bf16 hi+lo) | cnt | gmax | cand_val | cand_idx
    size_t af_elems = (size_t)Brows * KDIM * 2;
    unsigned short* af = (unsigned short*)d_ws;
    unsigned* cnt  = (unsigned*)(af + af_elems);
    unsigned* gmax = cnt + Brows;
    char* rest = (char*)(gmax + Brows);
    size_t used  = (size_t)(rest - (char*)d_ws);
    size_t avail = (ws_size > used) ? (ws_size - used) : 0;
    int cap = (int)((avail / ((size_t)Brows * 8)) < (size_t)MAXCAP
                        ? (avail / ((size_t)Brows * 8)) : (size_t)MAXCAP);
    if (cap < 1) cap = 1;
    float* cand_val = (float*)rest;
    int*   cand_idx = (int*)(cand_val + (size_t)Brows * cap);

    k_prep<<<(Brows * (KDIM / 8) + 255) / 256, 256, 0, stream>>>(A, af, cnt, gmax, Brows);
    k_gemm<<<(N + BN - 1) / BN, 256, 0, stream>>>(Bt, af, cand_val, cand_idx, cnt, gmax, N, cap);
    k_finalize<<<Brows, 256, 0, stream>>>(cand_val, cand_idx, cnt, gmax, labels, out, Brows, cap);
}

// Round 2
// 385.455 us; speedup vs baseline: 1.0695x; 1.0695x over previous
//
#include <hip/hip_runtime.h>
#include <math.h>

#define KDIM   512
#define NCLS   1000
#define CUTOFF 3.0f
#define MAXCAP 4096
#define BN     128
#define BK     64
#define NSTAGE (KDIM / BK)   // 8
#define FCAP   512

typedef __attribute__((ext_vector_type(8))) short  short8;
typedef __attribute__((ext_vector_type(4))) float  floatx4;

// ---- ordered-float <-> uint encoding for atomicMax on floats ----
__device__ __forceinline__ unsigned enc_f(float f) {
    unsigned u = __float_as_uint(f);
    return (u & 0x80000000u) ? ~u : (u | 0x80000000u);
}
__device__ __forceinline__ float dec_f(unsigned k) {
    unsigned u = (k & 0x80000000u) ? (k & 0x7FFFFFFFu) : ~k;
    return __uint_as_float(u);
}
// fp32 -> bf16 round-to-nearest-even
__device__ __forceinline__ unsigned short f2bf(float f) {
    unsigned u = __float_as_uint(f);
    u += 0x7FFFu + ((u >> 16) & 1u);
    return (unsigned short)(u >> 16);
}
__device__ __forceinline__ float bf2f(unsigned short h) {
    return __uint_as_float(((unsigned)h) << 16);
}

// Prep: init cnt/gmax; convert A (Brows x 512 fp32) into fragment-major bf16
// hi/lo: af slot (16B units) = ((s16*16 + c)*2 + h)*64 + lane,
// lane = kq*16 + (r&15), s16 = r>>4, c = k32-chunk, kq = k-octet within chunk.
__global__ void k_prep(const float* __restrict__ A, unsigned short* __restrict__ af,
                       unsigned* __restrict__ cnt, unsigned* __restrict__ gmax, int Brows) {
    int t = blockIdx.x * blockDim.x + threadIdx.x;
    if (t < Brows) { cnt[t] = 0u; gmax[t] = enc_f(-3.0e38f); }
    if (t >= Brows * (KDIM / 8)) return;
    int r = t >> 6;                 // row (64 k-octets per row)
    int o = t & 63;                 // k-octet index
    int s16 = r >> 4, c = o >> 2, kq = o & 3;
    int lane = kq * 16 + (r & 15);
    const float* src = A + (size_t)r * KDIM + o * 8;
    size_t bhi = ((size_t)((s16 * 16 + c) * 2 + 0) * 64 + lane) * 8;
    size_t blo = ((size_t)((s16 * 16 + c) * 2 + 1) * 64 + lane) * 8;
#pragma unroll
    for (int j = 0; j < 8; ++j) {
        float f = src[j];
        unsigned short h = f2bf(f);
        af[bhi + j] = h;
        af[blo + j] = f2bf(f - bf2f(h));
    }
}

// GEMM: block = 512 thr = 8 waves, covers ALL 256 rows (wave w: rows w*32..+32),
// BN=128 cols (two 64-col halves, each staged with the r0-proven conflict-free
// mapping; half 1 lives at LDS slot +512, bank-neutral). Full K=512.
// Split-bf16 3-pass MFMA. Double-buffered LDS (ONE barrier per stage -> half
// as many barrier-stages per CU as BN=64), B-prefetch distance 2, A-frag
// loads hoisted per chunk.
__global__ __launch_bounds__(512, 3) void k_gemm(
    const float* __restrict__ Bt,            // [N][512] fp32
    const unsigned short* __restrict__ af,   // A frags bf16 hi/lo
    float* __restrict__ cand_val, int* __restrict__ cand_idx,
    unsigned* __restrict__ cnt, unsigned* __restrict__ gmax,
    int N, int cap)
{
    __shared__ short8 BsH[2][1024];   // 2 x 16 KB
    __shared__ short8 BsL[2][1024];   // 2 x 16 KB

    const int tid  = threadIdx.x;
    const int lane = tid & 63;
    const int wid  = tid >> 6;                 // 0..7
    const int colBase = blockIdx.x * BN;

    // ---- B staging mapping (r0-identical per half): thread loads 8
    // consecutive k of col nl (half 0) and col nl+64 (half 1) ----
    const int nl  = tid >> 3;                  // 0..63 local col
    const int k8  = (tid & 7) * 8;             // k offset within stage
    const int gcol0 = colBase + nl;
    const int gcol1 = colBase + 64 + nl;
    const bool ok0 = (gcol0 < N);
    const bool ok1 = (gcol1 < N);
    const float* bsrc0 = Bt + (size_t)gcol0 * KDIM + k8;
    const float* bsrc1 = Bt + (size_t)gcol1 * KDIM + k8;
    const int chw = k8 >> 5;
    const int kqw = (k8 >> 3) & 3;
    const int ctw = (nl >> 4) & 3;
    const int fidw = chw * 4 + ctw;
    const int lfw  = kqw * 16 + (nl & 15);
    const int slotw = fidw * 64 + (lfw ^ (kqw * 2 + chw));

    floatx4 acc[2][8];
#pragma unroll
    for (int rt = 0; rt < 2; ++rt)
#pragma unroll
        for (int ct = 0; ct < 8; ++ct)
            acc[rt][ct] = (floatx4){0.f, 0.f, 0.f, 0.f};

    const float4 z4 = make_float4(0.f, 0.f, 0.f, 0.f);
    // c* = stage-s data (to convert now); n* = stage-(s+1) data (in flight)
    float4 c00 = ok0 ? *(const float4*)(bsrc0)          : z4;
    float4 c01 = ok0 ? *(const float4*)(bsrc0 + 4)      : z4;
    float4 c10 = ok1 ? *(const float4*)(bsrc1)          : z4;
    float4 c11 = ok1 ? *(const float4*)(bsrc1 + 4)      : z4;
    float4 n00 = ok0 ? *(const float4*)(bsrc0 + BK)     : z4;
    float4 n01 = ok0 ? *(const float4*)(bsrc0 + BK + 4) : z4;
    float4 n10 = ok1 ? *(const float4*)(bsrc1 + BK)     : z4;
    float4 n11 = ok1 ? *(const float4*)(bsrc1 + BK + 4) : z4;

    // convert one 8-float half-row and write to slot (+half offset)
    auto cvw = [&](int buf, int off, float4 a0, float4 a1) {
        union { float4 v[2]; float f[8]; } P;
        union { short8 v; unsigned short u[8]; } H, L;
        P.v[0] = a0; P.v[1] = a1;
#pragma unroll
        for (int j = 0; j < 8; ++j) {
            unsigned short h = f2bf(P.f[j]);
            H.u[j] = h; L.u[j] = f2bf(P.f[j] - bf2f(h));
        }
        BsH[buf][off + slotw] = H.v; BsL[buf][off + slotw] = L.v;
    };

    // convert + write stage 0 into buf 0
    cvw(0, 0,   c00, c01);
    cvw(0, 512, c10, c11);
    __syncthreads();

    for (int s = 0; s < NSTAGE; ++s) {
        // ---- stage s+1: move regs, issue prefetch of s+2, convert, LDS write ----
        if (s + 1 < NSTAGE) {
            c00 = n00; c01 = n01; c10 = n10; c11 = n11;
            if (s + 2 < NSTAGE) {
                const float* p0 = bsrc0 + (s + 2) * BK;
                const float* p1 = bsrc1 + (s + 2) * BK;
                n00 = ok0 ? *(const float4*)(p0)     : z4;
                n01 = ok0 ? *(const float4*)(p0 + 4) : z4;
                n10 = ok1 ? *(const float4*)(p1)     : z4;
                n11 = ok1 ? *(const float4*)(p1 + 4) : z4;
            }
            cvw((s + 1) & 1, 0,   c00, c01);
            cvw((s + 1) & 1, 512, c10, c11);
        }

        // ---- compute stage s from buf[s&1] ----
#pragma unroll
        for (int chunk = 0; chunk < 2; ++chunk) {
            const int cg = s * 2 + chunk;          // global k32 chunk
            short8 aH[2], aL[2];
#pragma unroll
            for (int rt = 0; rt < 2; ++rt) {       // hoisted ahead of MFMAs
                const int s16 = wid * 2 + rt;
                size_t sl = (size_t)((s16 * 16 + cg) * 2) * 64 + lane;
                aH[rt] = *(const short8*)(af + sl * 8);
                aL[rt] = *(const short8*)(af + (sl + 64) * 8);
            }
            const int g = (lane >> 4) * 2 + chunk; // reader XOR swizzle
#pragma unroll
            for (int ct = 0; ct < 8; ++ct) {
                const int idx = (chunk * 4 + (ct & 3)) * 64 + (lane ^ g) + ((ct & 4) ? 512 : 0);
                short8 bh = BsH[s & 1][idx];
                short8 bl = BsL[s & 1][idx];
#pragma unroll
                for (int rt = 0; rt < 2; ++rt) {
                    acc[rt][ct] = __builtin_amdgcn_mfma_f32_16x16x32_bf16(aH[rt], bh, acc[rt][ct], 0, 0, 0);
                    acc[rt][ct] = __builtin_amdgcn_mfma_f32_16x16x32_bf16(aH[rt], bl, acc[rt][ct], 0, 0, 0);
                    acc[rt][ct] = __builtin_amdgcn_mfma_f32_16x16x32_bf16(aL[rt], bh, acc[rt][ct], 0, 0, 0);
                }
            }
        }
        __syncthreads();
    }

    // ---- epilogue: chunk max, running global max, candidate append ----
    // C/D layout (verified): col = lane&15, row = (lane>>4)*4 + reg
    const int q   = lane >> 4;
    const int n15 = lane & 15;
#pragma unroll
    for (int rt = 0; rt < 2; ++rt) {
#pragma unroll
        for (int reg = 0; reg < 4; ++reg) {
            const int row = wid * 32 + rt * 16 + q * 4 + reg;
            float m = acc[rt][0][reg];
#pragma unroll
            for (int ct = 1; ct < 8; ++ct) m = fmaxf(m, acc[rt][ct][reg]);
#pragma unroll
            for (int off = 1; off < 16; off <<= 1) m = fmaxf(m, __shfl_xor(m, off));
            unsigned oldk = 0u;
            if (n15 == 0) oldk = atomicMax(&gmax[row], enc_f(m));
            oldk = (unsigned)__shfl((int)oldk, lane & 48);   // quad leader
            const float thr = fmaxf(dec_f(oldk), m) - CUTOFF;
#pragma unroll
            for (int ct = 0; ct < 8; ++ct) {
                const float v = acc[rt][ct][reg];
                const int col = colBase + ((ct & 4) ? 64 : 0) + (ct & 3) * 16 + n15;
                if (v >= thr && col < N) {
                    unsigned p = atomicAdd(&cnt[row], 1u);
                    if (p < (unsigned)cap) {
                        cand_val[(size_t)row * cap + p] = v;
                        cand_idx[(size_t)row * cap + p] = col;
                    }
                }
            }
        }
    }
}

// One block per row. Parallel: compact survivors (thr = gmax-CUTOFF) into LDS,
// rank each candidate by counting (O(ns^2) over 256 threads, ns is tiny),
// deterministic Z reduction, scatter weights into a 16 KB per-row LDS image
// of all 4 k-slices, write back coalesced (covers the full output row, so no
// separate zeroing pass).
__global__ __launch_bounds__(256) void k_finalize(
    const float* __restrict__ cand_val,
    const int* __restrict__ cand_idx,
    const unsigned* __restrict__ cnt,
    const unsigned* __restrict__ gmax,
    const int* __restrict__ labels,
    float* __restrict__ out,
    int Brows, int cap)
{
    __shared__ float s_val[FCAP];
    __shared__ int   s_idx[FCAP];
    __shared__ float s_out[4 * NCLS];   // 16 KB
    __shared__ int   s_n;
    __shared__ float s_part[4];
    __shared__ float s_Z;

    const int row = blockIdx.x;
    const int tid = threadIdx.x;
    if (tid == 0) s_n = 0;
    __syncthreads();

    const float m   = dec_f(gmax[row]);
    const float thr = m - CUTOFF;
    const int n = min((int)cnt[row], cap);
    for (int i = tid; i < n; i += 256) {
        float v = cand_val[(size_t)row * cap + i];
        if (v >= thr) {
            int p = atomicAdd(&s_n, 1);
            if (p < FCAP) { s_val[p] = v; s_idx[p] = cand_idx[(size_t)row * cap + i]; }
        }
    }
    for (int c = tid; c < 4 * NCLS; c += 256) s_out[c] = 0.f;
    __syncthreads();
    const int ns = min(s_n, FCAP);

    // rank-by-counting; each thread owns candidates tid and tid+256
    float e0 = 0.f, e1 = 0.f;
    int   r0 = 0x7fffffff, r1 = 0x7fffffff;
    int   lab0 = 0, lab1 = 0;
    if (tid < ns) {
        const float v = s_val[tid]; const int ix = s_idx[tid];
        int rk = 0;
        for (int j = 0; j < ns; ++j) {
            const float vj = s_val[j];
            rk += (vj > v || (vj == v && s_idx[j] < ix)) ? 1 : 0;
        }
        r0 = rk;
        if (rk < 200) { e0 = expf((v - m) * (1.0f / 0.07f)); lab0 = labels[ix]; }
    }
    if (tid + 256 < ns) {
        const int i2 = tid + 256;
        const float v = s_val[i2]; const int ix = s_idx[i2];
        int rk = 0;
        for (int j = 0; j < ns; ++j) {
            const float vj = s_val[j];
            rk += (vj > v || (vj == v && s_idx[j] < ix)) ? 1 : 0;
        }
        r1 = rk;
        if (rk < 200) { e1 = expf((v - m) * (1.0f / 0.07f)); lab1 = labels[ix]; }
    }

    // deterministic Z: wave shfl reduce + fixed-order cross-wave sum
    float part = e0 + e1;
#pragma unroll
    for (int off = 32; off >= 1; off >>= 1) part += __shfl_down(part, off);
    if ((tid & 63) == 0) s_part[tid >> 6] = part;
    __syncthreads();
    if (tid == 0) s_Z = (s_part[0] + s_part[1]) + (s_part[2] + s_part[3]);
    __syncthreads();
    const float invZ = 1.0f / s_Z;

    if (r0 < 200) {
        const float w = e0 * invZ;
        if (r0 < 10)  atomicAdd(&s_out[0 * NCLS + lab0], w);
        if (r0 < 20)  atomicAdd(&s_out[1 * NCLS + lab0], w);
        if (r0 < 100) atomicAdd(&s_out[2 * NCLS + lab0], w);
        atomicAdd(&s_out[3 * NCLS + lab0], w);
    }
    if (r1 < 200) {
        const float w = e1 * invZ;
        if (r1 < 10)  atomicAdd(&s_out[0 * NCLS + lab1], w);
        if (r1 < 20)  atomicAdd(&s_out[1 * NCLS + lab1], w);
        if (r1 < 100) atomicAdd(&s_out[2 * NCLS + lab1], w);
        atomicAdd(&s_out[3 * NCLS + lab1], w);
    }
    __syncthreads();

    for (int c = tid; c < 4 * NCLS; c += 256) {
        const int sl = c / NCLS, cc = c - sl * NCLS;
        out[(size_t)sl * ((size_t)Brows * NCLS) + (size_t)row * NCLS + cc] = s_out[c];
    }
}

extern "C" void kernel_launch(void* const* d_in, const int* in_sizes, int n_in,
                              void* d_out, int out_size, void* d_ws, size_t ws_size,
                              hipStream_t stream) {
    const float* A      = (const float*)d_in[0];   // (256, 512)
    const float* Bt     = (const float*)d_in[1];   // (100000, 512)
    const int*   labels = (const int*)d_in[2];     // (100000,)
    float* out = (float*)d_out;                    // (4, 256, 1000)

    const int Brows = in_sizes[0] / KDIM;          // 256
    const int N     = in_sizes[2];                 // 100000

    // ws layout: af (Brows*512*2 bf16 hi+lo) | cnt | gmax | cand_val | cand_idx
    size_t af_elems = (size_t)Brows * KDIM * 2;
    unsigned short* af = (unsigned short*)d_ws;
    unsigned* cnt  = (unsigned*)(af + af_elems);
    unsigned* gmax = cnt + Brows;
    char* rest = (char*)(gmax + Brows);
    size_t used  = (size_t)(rest - (char*)d_ws);
    size_t avail = (ws_size > used) ? (ws_size - used) : 0;
    int cap = (int)((avail / ((size_t)Brows * 8)) < (size_t)MAXCAP
                        ? (avail / ((size_t)Brows * 8)) : (size_t)MAXCAP);
    if (cap < 1) cap = 1;
    float* cand_val = (float*)rest;
    int*   cand_idx = (int*)(cand_val + (size_t)Brows * cap);

    k_prep<<<(Brows * (KDIM / 8) + 255) / 256, 256, 0, stream>>>(A, af, cnt, gmax, Brows);
    k_gemm<<<(N + BN - 1) / BN, 512, 0, stream>>>(Bt, af, cand_val, cand_idx, cnt, gmax, N, cap);
    k_finalize<<<Brows, 256, 0, stream>>>(cand_val, cand_idx, cnt, gmax, labels, out, Brows, cap);
}